// Round 4
// baseline (321.962 us; speedup 1.0000x reference)
//
#include <hip/hip_runtime.h>
#include <cstdint>

// Problem constants
#define NB 32
#define IC 256
#define OC 256
#define H 56
#define WIDTH 56
#define OH 54
#define OW 54
#define HW (H*WIDTH)          // 3136
#define OHW (OH*OW)           // 2916
#define KTOT 2304             // 9 * 256, k = (kh*3+kw)*256 + c
#define M_TOT (NB*OHW)        // 93312
#define C8N (IC/8)            // 32 chunks of 8 channels

// GEMM tiling
#define BM 128                // spatial tile
#define BO 256                // out-channel tile (= all of OC: X staged once)
#define BK 32
#define KSTEPS (KTOT/BK)      // 72
#define MBLOCKS (M_TOT/BM)    // 729
#define XBLK ((NB*C8N*HW)/256)  // 12544 xform blocks

// weights pre-tiled as per-K-step LDS images WITH chunk swizzle:
// g_qwt[step][r][cs][b] = sign(W[o=r][k = step*32 + (cs ^ ((r>>1)&3))*8 + b])
__device__ __align__(16) unsigned short g_qwt[KSTEPS*BO*BK];
// x as [n][c8][hw][8] bf16 (16B granule = 8 consecutive channels at one pixel)
__device__ __align__(16) unsigned short g_xq[NB*C8N*HW*8];

typedef __bf16 bf16x8 __attribute__((ext_vector_type(8)));
typedef float  f32x16 __attribute__((ext_vector_type(16)));

typedef __attribute__((address_space(1))) const unsigned int gas_u32;
typedef __attribute__((address_space(3))) unsigned int las_u32;
__device__ __forceinline__ void async_copy16(const void* g, void* l) {
  // global -> LDS direct copy, 16 B per lane; LDS dst = wave-uniform base + lane*16
  __builtin_amdgcn_global_load_lds((gas_u32*)g, (las_u32*)l, 16, 0, 0);
}

__device__ inline unsigned short f32_bf16(float f) {
  union { float f; unsigned int u; } v; v.f = f;
  unsigned int u = v.u;
  return (unsigned short)((u + 0x7FFFu + ((u >> 16) & 1u)) >> 16);  // RNE
}

// Counted vmcnt wait (T4): N outstanding VMEM ops may remain in flight.
#define WAITV(N) asm volatile("s_waitcnt vmcnt(" #N ")" ::: "memory")
// Raw barrier (no implicit vmcnt(0) drain, unlike __syncthreads()).
#define BARRIER() do { \
  __builtin_amdgcn_sched_barrier(0); \
  __builtin_amdgcn_s_barrier(); \
  __builtin_amdgcn_sched_barrier(0); \
} while (0)

// ---- Kernel 1: fused prep (x transform + weight repack), one launch ------
__global__ __launch_bounds__(256) void prep(const float* __restrict__ x,
                                            const float* __restrict__ w) {
  const int t = threadIdx.x;
  if (blockIdx.x < XBLK) {
    // x NCHW fp32 -> [n][c8][hw][8] bf16, LDS-free.
    int g = blockIdx.x * 256 + t;                   // granule id, < 3211264
    int hw = g % HW;
    int tc = g / HW;                                // n*32 + c8
    int c8 = tc & 31;
    int n  = tc >> 5;
    const float* src = x + (n*IC + c8*8)*HW + hw;
    unsigned int o[4];
    #pragma unroll
    for (int j = 0; j < 4; ++j) {
      unsigned int lo = f32_bf16(src[(2*j+0)*HW]);
      unsigned int hi = f32_bf16(src[(2*j+1)*HW]);
      o[j] = lo | (hi << 16);
    }
    *(uint4*)(&g_xq[g*8]) = *(uint4*)o;
  } else {
    // binarize + pre-tile weights (swizzled LDS image)
    int L = (blockIdx.x - XBLK) * 256 + t;          // < 589824
    int step = L >> 13;                             // /8192 (256 rows * 32 k)
    int r    = (L >> 5) & 255;
    int kc   = L & 31;
    int cs   = kc >> 3;                             // chunk slot 0..3
    int b    = kc & 7;
    int csrc = cs ^ ((r >> 1) & 3);                 // bank-conflict swizzle
    int k    = step*BK + csrc*8 + b;
    int pos  = k >> 8;                              // kh*3+kw
    int c    = k & 255;
    float v = w[r*2304 + c*9 + pos];
    g_qwt[L] = (v > 0.f) ? 0x3F80u : ((v < 0.f) ? 0xBF80u : 0u);
  }
}

// ---- Kernel 2: implicit-GEMM binary conv, 256o x 128m tile ---------------
// 8 waves (4 o-groups x 2 m-groups, 64x64 each), BK=32, 32x32x16 MFMA.
// 3-deep circular LDS pipeline, ONE barrier per K-step (post-compute):
//   iter s: STAGE(s+2)->buf[(s+2)%3] (freed by prev barrier); COMPUTE(s);
//           WAITV(3) (stage s+1 landed); BARRIER.
// Tile s's data is thus guaranteed one full iteration before its compute.
__global__ __launch_bounds__(512, 4) void bconv_gemm(float* __restrict__ out) {
  __shared__ __align__(16) unsigned short Wl[3][BO*BK];   // 3 x 16 KB
  __shared__ __align__(16) unsigned short Xl[3][BM*BK];   // 3 x  8 KB  (72 KB)
  const int t = threadIdx.x;

  // XCD-aware bijective remap (729 = 8*91 + 1; xcd 0 gets 92 tiles).
  const int orig = blockIdx.x;
  const int xcd  = orig & 7;
  const int idx  = orig >> 3;
  const int bm   = (xcd == 0) ? idx : (92 + (xcd - 1)*91 + idx);
  const int m0   = bm * BM;

  // X staging: thread owns chunk q=t of 512. row i=q>>2, slot cs=q&3.
  // Source chunk pre-swizzled (cs ^ ((i>>1)&3)) -> linear LDS dest holds the
  // swizzled layout (linear dest + pre-swizzled source + swizzled read).
  int xbase;
  {
    const int i   = t >> 2;                         // m-row 0..127
    const int cs  = t & 3;
    const int csw = cs ^ ((i >> 1) & 3);
    int m  = m0 + i;
    int n  = m / OHW;
    int rm = m - n*OHW;
    int oh = rm / OW;
    int ow = rm - oh*OW;
    xbase = ((n*C8N + csw)*HW + oh*WIDTH + ow) * 8;
  }

  const int lane = t & 63;
  const int wv   = t >> 6;                          // 0..7
  const int r5   = lane & 31;
  const int half = lane >> 5;                       // 0/1 -> k-subchunk
  const int wo   = (wv >> 1) * 64;                  // wave o-offset (0,64,128,192)
  const int wm   = (wv & 1) * 64;                   // wave m-offset (0,64)
  // read-side swizzle: row = (multiple of 32) + r5 -> ((row>>1)&3)==((r5>>1)&3)
  const int swz  = (r5 >> 1) & 3;
  int koff[2];
  #pragma unroll
  for (int kk = 0; kk < 2; ++kk)
    koff[kk] = (((kk << 1) | half) ^ swz) * 8;      // physical 8-elem chunk
  const int aRow = (wo + r5) * BK;                  // + ot*1024 (imm) + koff
  const int bRow = (wm + r5) * BK;                  // + mt*1024 (imm) + koff

  auto STAGE = [&](int step, int buf) {
    const unsigned short* ws = g_qwt + step*(BO*BK);
    async_copy16(&ws[t*8],       &Wl[buf][t*8]);         // W: 1024 chunks, linear
    async_copy16(&ws[(t+512)*8], &Wl[buf][(t+512)*8]);
    const int pos = step >> 3;                            // 8 steps per position
    const int kh  = pos / 3;
    const int kw  = pos - kh*3;
    const int xo  = xbase + (((step & 7)*4)*HW + kh*WIDTH + kw)*8;
    async_copy16(&g_xq[xo], &Xl[buf][t*8]);               // X: im2col gather
  };

  f32x16 acc[2][2];
  #pragma unroll
  for (int a = 0; a < 2; ++a)
    #pragma unroll
    for (int b = 0; b < 2; ++b)
      acc[a][b] = (f32x16)0.f;

  auto COMPUTE = [&](const unsigned short* Wb, const unsigned short* Xb) {
    bf16x8 av[2][2], bv[2][2];
    #pragma unroll
    for (int kk = 0; kk < 2; ++kk) {
      #pragma unroll
      for (int ot = 0; ot < 2; ++ot)
        av[ot][kk] = *(const bf16x8*)(&Wb[aRow + ot*(32*BK) + koff[kk]]);
      #pragma unroll
      for (int mt = 0; mt < 2; ++mt)
        bv[mt][kk] = *(const bf16x8*)(&Xb[bRow + mt*(32*BK) + koff[kk]]);
    }
    __builtin_amdgcn_s_setprio(1);
    #pragma unroll
    for (int kk = 0; kk < 2; ++kk)
      #pragma unroll
      for (int ot = 0; ot < 2; ++ot)
        #pragma unroll
        for (int mt = 0; mt < 2; ++mt)
          acc[ot][mt] = __builtin_amdgcn_mfma_f32_32x32x16_bf16(
              av[ot][kk], bv[mt][kk], acc[ot][mt], 0, 0, 0);
    __builtin_amdgcn_s_setprio(0);
  };

  // Prologue: stages 0,1 in flight; ensure 0 landed everywhere.
  STAGE(0, 0);
  STAGE(1, 1);
  WAITV(3);
  BARRIER();

  // Main loop: tiles 0..68 (23 x3), staging to s+4 <= 70.
  #pragma unroll 1
  for (int s = 0; s < 69; s += 3) {
    STAGE(s + 2, 2); __builtin_amdgcn_sched_barrier(0);
    COMPUTE(Wl[0], Xl[0]);                // tile s
    WAITV(3);
    BARRIER();

    STAGE(s + 3, 0); __builtin_amdgcn_sched_barrier(0);
    COMPUTE(Wl[1], Xl[1]);                // tile s+1
    WAITV(3);
    BARRIER();

    STAGE(s + 4, 1); __builtin_amdgcn_sched_barrier(0);
    COMPUTE(Wl[2], Xl[2]);                // tile s+2
    WAITV(3);
    BARRIER();
  }

  // Tail: tiles 69, 70, 71.
  STAGE(71, 2); __builtin_amdgcn_sched_barrier(0);
  COMPUTE(Wl[0], Xl[0]);                  // tile 69
  WAITV(3);
  BARRIER();
  COMPUTE(Wl[1], Xl[1]);                  // tile 70
  WAITV(0);
  BARRIER();
  COMPUTE(Wl[2], Xl[2]);                  // tile 71

  // Epilogue: 32x32 C/D layout: col(m)=lane&31, row(o)=4*half+(reg&3)+8*(reg>>2).
  #pragma unroll
  for (int mt = 0; mt < 2; ++mt) {
    int m  = m0 + wm + mt*32 + r5;
    int n  = m / OHW;
    int rm = m - n*OHW;
    float* obase = out + n*(OC*OHW) + rm;
    #pragma unroll
    for (int ot = 0; ot < 2; ++ot) {
      int o0 = wo + ot*32 + half*4;
      #pragma unroll
      for (int reg = 0; reg < 16; ++reg) {
        int o = o0 + (reg & 3) + 8*(reg >> 2);
        obase[o*OHW] = acc[ot][mt][reg];
      }
    }
  }
}

extern "C" void kernel_launch(void* const* d_in, const int* in_sizes, int n_in,
                              void* d_out, int out_size, void* d_ws, size_t ws_size,
                              hipStream_t stream) {
  const float* x = (const float*)d_in[0];   // [32,256,56,56] fp32
  const float* w = (const float*)d_in[1];   // [256,256,3,3] fp32
  float* out = (float*)d_out;               // [32,256,54,54] fp32

  prep<<<dim3(XBLK + (KSTEPS*BO*BK)/256), 256, 0, stream>>>(x, w);  // 14848 blocks
  bconv_gemm<<<dim3(MBLOCKS), 512, 0, stream>>>(out);               // 729 blocks
}

// Round 5
// 309.880 us; speedup vs baseline: 1.0390x; 1.0390x over previous
//
#include <hip/hip_runtime.h>
#include <cstdint>

// Problem constants
#define NB 32
#define IC 256
#define OC 256
#define H 56
#define WIDTH 56
#define OH 54
#define OW 54
#define HW (H*WIDTH)          // 3136
#define OHW (OH*OW)           // 2916
#define KTOT 2304             // 9 * 256, k = (kh*3+kw)*256 + c
#define M_TOT (NB*OHW)        // 93312
#define C8N (IC/8)            // 32 chunks of 8 channels

// GEMM tiling
#define BM 128                // spatial tile
#define BO 256                // out-channel tile (= all of OC: X staged once)
#define BK 32
#define KSTEPS (KTOT/BK)      // 72
#define MBLOCKS (M_TOT/BM)    // 729
#define XBLK ((NB*C8N*HW)/256)  // 12544 xform blocks

// weights pre-tiled as per-K-step LDS images WITH chunk swizzle:
// g_qwt[step][r][cs][b] = sign(W[o=r][k = step*32 + (cs ^ ((r>>1)&3))*8 + b])
__device__ __align__(16) unsigned short g_qwt[KSTEPS*BO*BK];
// x as [n][c8][hw][8] bf16 (16B granule = 8 consecutive channels at one pixel)
__device__ __align__(16) unsigned short g_xq[NB*C8N*HW*8];

typedef __bf16 bf16x8 __attribute__((ext_vector_type(8)));
typedef float  f32x4  __attribute__((ext_vector_type(4)));

typedef __attribute__((address_space(1))) const unsigned int gas_u32;
typedef __attribute__((address_space(3))) unsigned int las_u32;
__device__ __forceinline__ void async_copy16(const void* g, void* l) {
  // global -> LDS direct copy, 16 B per lane; LDS dst = wave-uniform base + lane*16
  __builtin_amdgcn_global_load_lds((gas_u32*)g, (las_u32*)l, 16, 0, 0);
}

__device__ inline unsigned short f32_bf16(float f) {
  union { float f; unsigned int u; } v; v.f = f;
  unsigned int u = v.u;
  return (unsigned short)((u + 0x7FFFu + ((u >> 16) & 1u)) >> 16);  // RNE
}

// Counted vmcnt wait (T4): N outstanding VMEM ops may remain in flight.
#define WAITV(N) asm volatile("s_waitcnt vmcnt(" #N ")" ::: "memory")
// Raw barrier (no implicit vmcnt(0) drain, unlike __syncthreads()).
#define BARRIER() do { \
  __builtin_amdgcn_sched_barrier(0); \
  __builtin_amdgcn_s_barrier(); \
  __builtin_amdgcn_sched_barrier(0); \
} while (0)

// ---- Kernel 1: fused prep (x transform + weight repack), one launch ------
__global__ __launch_bounds__(256) void prep(const float* __restrict__ x,
                                            const float* __restrict__ w) {
  const int t = threadIdx.x;
  if (blockIdx.x < XBLK) {
    // x NCHW fp32 -> [n][c8][hw][8] bf16, LDS-free.
    int g = blockIdx.x * 256 + t;                   // granule id, < 3211264
    int hw = g % HW;
    int tc = g / HW;                                // n*32 + c8
    int c8 = tc & 31;
    int n  = tc >> 5;
    const float* src = x + (n*IC + c8*8)*HW + hw;
    unsigned int o[4];
    #pragma unroll
    for (int j = 0; j < 4; ++j) {
      unsigned int lo = f32_bf16(src[(2*j+0)*HW]);
      unsigned int hi = f32_bf16(src[(2*j+1)*HW]);
      o[j] = lo | (hi << 16);
    }
    *(uint4*)(&g_xq[g*8]) = *(uint4*)o;
  } else {
    // binarize + pre-tile weights (swizzled LDS image)
    int L = (blockIdx.x - XBLK) * 256 + t;          // < 589824
    int step = L >> 13;                             // /8192 (256 rows * 32 k)
    int r    = (L >> 5) & 255;
    int kc   = L & 31;
    int cs   = kc >> 3;                             // chunk slot 0..3
    int b    = kc & 7;
    int csrc = cs ^ ((r >> 1) & 3);                 // bank-conflict swizzle
    int k    = step*BK + csrc*8 + b;
    int pos  = k >> 8;                              // kh*3+kw
    int c    = k & 255;
    float v = w[r*2304 + c*9 + pos];
    g_qwt[L] = (v > 0.f) ? 0x3F80u : ((v < 0.f) ? 0xBF80u : 0u);
  }
}

// ---- Kernel 2: implicit-GEMM binary conv, 256o x 128m tile ---------------
// 8 waves (4 o-groups x 2 m-groups, 64x64 each), BK=32, 16x16x32 MFMA
// (the 16-row fragment pattern measured ZERO LDS bank conflicts; the 32x32
//  variant measured 4 extra cyc/ds_read_b128 -- reverted).
// 3-deep circular LDS pipeline, ONE barrier per K-step (post-compute):
//   iter s: STAGE(s+2)->buf[(s+2)%3] (freed by prev barrier); COMPUTE(s);
//           WAITV(3) (=> stage s+1 landed); BARRIER.
__global__ __launch_bounds__(512, 4) void bconv_gemm(float* __restrict__ out) {
  __shared__ __align__(16) unsigned short Wl[3][BO*BK];   // 3 x 16 KB
  __shared__ __align__(16) unsigned short Xl[3][BM*BK];   // 3 x  8 KB  (72 KB)
  const int t = threadIdx.x;

  // XCD-aware bijective remap (729 = 8*91 + 1; xcd 0 gets 92 tiles).
  const int orig = blockIdx.x;
  const int xcd  = orig & 7;
  const int idx  = orig >> 3;
  const int bm   = (xcd == 0) ? idx : (92 + (xcd - 1)*91 + idx);
  const int m0   = bm * BM;

  // X staging: thread owns chunk q=t of 512. row i=q>>2, slot cs=q&3.
  // Source chunk pre-swizzled (cs ^ ((i>>1)&3)) -> linear LDS dest holds the
  // swizzled layout (linear dest + pre-swizzled source + swizzled read).
  int xbase;
  {
    const int i   = t >> 2;                         // m-row 0..127
    const int cs  = t & 3;
    const int csw = cs ^ ((i >> 1) & 3);
    int m  = m0 + i;
    int n  = m / OHW;
    int rm = m - n*OHW;
    int oh = rm / OW;
    int ow = rm - oh*OW;
    xbase = ((n*C8N + csw)*HW + oh*WIDTH + ow) * 8;
  }

  const int lane = t & 63;
  const int wv   = t >> 6;                          // 0..7
  const int col  = lane & 15;
  const int quad = lane >> 4;
  const int wo   = (wv >> 1) * 64;                  // wave o-offset (0,64,128,192)
  const int wm   = (wv & 1) * 64;                   // wave m-offset (0,64)
  // read-side swizzle: rows are (multiple of 16)+col -> ((row>>1)&3)==((col>>1)&3)
  const int sw   = (quad ^ ((col >> 1) & 3)) * 8;
  int aoff[4], boff[4];
  #pragma unroll
  for (int i = 0; i < 4; ++i) {
    aoff[i] = (wo + i*16 + col)*BK + sw;
    boff[i] = (wm + i*16 + col)*BK + sw;
  }

  auto STAGE = [&](int step, int buf) {
    const unsigned short* ws = g_qwt + step*(BO*BK);
    async_copy16(&ws[t*8],       &Wl[buf][t*8]);         // W: 1024 chunks, linear
    async_copy16(&ws[(t+512)*8], &Wl[buf][(t+512)*8]);
    const int pos = step >> 3;                            // 8 steps per position
    const int kh  = pos / 3;
    const int kw  = pos - kh*3;
    const int xo  = xbase + (((step & 7)*4)*HW + kh*WIDTH + kw)*8;
    async_copy16(&g_xq[xo], &Xl[buf][t*8]);               // X: im2col gather
  };

  f32x4 acc[4][4];
  #pragma unroll
  for (int a = 0; a < 4; ++a)
    #pragma unroll
    for (int b = 0; b < 4; ++b)
      acc[a][b] = (f32x4){0.f, 0.f, 0.f, 0.f};

  auto COMPUTE = [&](const unsigned short* Wb, const unsigned short* Xb) {
    bf16x8 av[4], bv[4];
    #pragma unroll
    for (int i = 0; i < 4; ++i) av[i] = *(const bf16x8*)(&Wb[aoff[i]]);
    #pragma unroll
    for (int i = 0; i < 4; ++i) bv[i] = *(const bf16x8*)(&Xb[boff[i]]);
    __builtin_amdgcn_s_setprio(1);
    #pragma unroll
    for (int io = 0; io < 4; ++io)
      #pragma unroll
      for (int im = 0; im < 4; ++im)
        acc[io][im] = __builtin_amdgcn_mfma_f32_16x16x32_bf16(av[io], bv[im], acc[io][im], 0, 0, 0);
    __builtin_amdgcn_s_setprio(0);
  };

  // Prologue: stages 0,1 in flight; ensure 0 landed everywhere.
  STAGE(0, 0);
  STAGE(1, 1);
  WAITV(3);
  BARRIER();

  // Main loop: tiles 0..68 (23 iters x3), staging up to s+4 <= 70.
  #pragma unroll 1
  for (int s = 0; s < 69; s += 3) {
    STAGE(s + 2, 2); __builtin_amdgcn_sched_barrier(0);
    COMPUTE(Wl[0], Xl[0]);                // tile s
    WAITV(3);
    BARRIER();

    STAGE(s + 3, 0); __builtin_amdgcn_sched_barrier(0);
    COMPUTE(Wl[1], Xl[1]);                // tile s+1
    WAITV(3);
    BARRIER();

    STAGE(s + 4, 1); __builtin_amdgcn_sched_barrier(0);
    COMPUTE(Wl[2], Xl[2]);                // tile s+2
    WAITV(3);
    BARRIER();
  }

  // Tail: tiles 69, 70, 71.
  STAGE(71, 2); __builtin_amdgcn_sched_barrier(0);
  COMPUTE(Wl[0], Xl[0]);                  // tile 69
  WAITV(3);
  BARRIER();
  COMPUTE(Wl[1], Xl[1]);                  // tile 70
  WAITV(0);
  BARRIER();
  COMPUTE(Wl[2], Xl[2]);                  // tile 71

  // Epilogue: D col=(lane&15)->m, row=(quad*4+r)->o. out[n][o][oh][ow].
  #pragma unroll
  for (int im = 0; im < 4; ++im) {
    int m  = m0 + wm + im*16 + col;
    int n  = m / OHW;
    int rm = m - n*OHW;
    float* obase = out + n*(OC*OHW) + rm;
    #pragma unroll
    for (int io = 0; io < 4; ++io) {
      int orow = wo + io*16 + quad*4;
      #pragma unroll
      for (int r = 0; r < 4; ++r)
        obase[(orow + r)*OHW] = acc[io][im][r];
    }
  }
}

extern "C" void kernel_launch(void* const* d_in, const int* in_sizes, int n_in,
                              void* d_out, int out_size, void* d_ws, size_t ws_size,
                              hipStream_t stream) {
  const float* x = (const float*)d_in[0];   // [32,256,56,56] fp32
  const float* w = (const float*)d_in[1];   // [256,256,3,3] fp32
  float* out = (float*)d_out;               // [32,256,54,54] fp32

  prep<<<dim3(XBLK + (KSTEPS*BO*BK)/256), 256, 0, stream>>>(x, w);  // 14848 blocks
  bconv_gemm<<<dim3(MBLOCKS), 512, 0, stream>>>(out);               // 729 blocks
}